// Round 2
// baseline (219.023 us; speedup 1.0000x reference)
//
#include <hip/hip_runtime.h>
#include <math.h>

#define B_ 32
#define C_ 256
#define HW_ 3136      // 56*56
#define HW4_ 784      // HW/4 (float4 = 16B chunks)
#define G_ 32
#define EPS_ 1e-5f

// K1: pooled[b,c] = mean over HW of x[b,c,:,:]   (one block per (b,c) plane)
__global__ __launch_bounds__(256) void pool_kernel(const float* __restrict__ x,
                                                   float* __restrict__ pooled) {
    const int bc = blockIdx.x;
    const float4* __restrict__ p = (const float4*)(x + (size_t)bc * HW_);
    const int tid = threadIdx.x;
    float s = 0.f;
    for (int i = tid; i < HW4_; i += 256) {
        float4 v = p[i];
        s += v.x + v.y + v.z + v.w;
    }
    // wave (64) shuffle reduce
    #pragma unroll
    for (int off = 32; off; off >>= 1) s += __shfl_down(s, off);
    __shared__ float red[4];
    const int lane = tid & 63, wv = tid >> 6;
    if (lane == 0) red[wv] = s;
    __syncthreads();
    if (tid == 0) {
        float t = red[0] + red[1] + red[2] + red[3];
        pooled[bc] = t * (1.f / HW_);
    }
}

// K2: per-batch alpha + fold all norm params into per-(b,c) scale/shift
__global__ __launch_bounds__(256) void alpha_scale_kernel(
    const float* __restrict__ pooled,
    const float* __restrict__ alpha_w, const float* __restrict__ alpha_b,
    const float* __restrict__ g_w, const float* __restrict__ g_b,
    const float* __restrict__ g_rm, const float* __restrict__ g_rv,
    const float* __restrict__ grp_w, const float* __restrict__ grp_b,
    const float* __restrict__ grp_rm, const float* __restrict__ grp_rv,
    float* __restrict__ scale, float* __restrict__ shift) {
    const int b = blockIdx.x;
    const int c = threadIdx.x;   // 256 threads == C
    // dot(pooled[b,:], alpha_w)
    float s = pooled[b * C_ + c] * alpha_w[c];
    #pragma unroll
    for (int off = 32; off; off >>= 1) s += __shfl_down(s, off);
    __shared__ float red[4];
    __shared__ float alpha_sh;
    const int lane = c & 63, wv = c >> 6;
    if (lane == 0) red[wv] = s;
    __syncthreads();
    if (c == 0) {
        float z = red[0] + red[1] + red[2] + red[3] + alpha_b[0];
        alpha_sh = 1.f / (1.f + expf(-z));
    }
    __syncthreads();
    const float a = alpha_sh;

    // global-BN affine
    float gs  = g_w[c] * rsqrtf(g_rv[c] + EPS_);
    float gsh = g_b[c] - g_rm[c] * gs;
    // group-mixture affine (mean over G)
    float mss = 0.f, mshs = 0.f;
    #pragma unroll 8
    for (int g = 0; g < G_; ++g) {
        float sg = grp_w[g * C_ + c] * rsqrtf(grp_rv[g * C_ + c] + EPS_);
        mss  += sg;
        mshs += grp_b[g * C_ + c] - grp_rm[g * C_ + c] * sg;
    }
    float ms  = mss  * (1.f / G_);
    float msh = mshs * (1.f / G_);

    scale[b * C_ + c] = (1.f - a) * gs  + a * ms;
    shift[b * C_ + c] = (1.f - a) * gsh + a * msh;
}

// K3: out = x * scale[bc] + shift[bc]   (one block per (b,c) plane)
__global__ __launch_bounds__(256) void apply_kernel(const float* __restrict__ x,
                                                    const float* __restrict__ scale,
                                                    const float* __restrict__ shift,
                                                    float* __restrict__ out) {
    const int bc = blockIdx.x;
    const float sc = scale[bc];
    const float sh = shift[bc];
    const float4* __restrict__ px = (const float4*)(x + (size_t)bc * HW_);
    float4* __restrict__ po = (float4*)(out + (size_t)bc * HW_);
    for (int i = threadIdx.x; i < HW4_; i += 256) {
        float4 v = px[i];
        float4 r;
        r.x = fmaf(v.x, sc, sh);
        r.y = fmaf(v.y, sc, sh);
        r.z = fmaf(v.z, sc, sh);
        r.w = fmaf(v.w, sc, sh);
        po[i] = r;
    }
}

extern "C" void kernel_launch(void* const* d_in, const int* in_sizes, int n_in,
                              void* d_out, int out_size, void* d_ws, size_t ws_size,
                              hipStream_t stream) {
    const float* x       = (const float*)d_in[0];
    // d_in[1] = labels (int32) — unused by the reference output
    const float* alpha_w = (const float*)d_in[2];
    const float* alpha_b = (const float*)d_in[3];
    const float* g_w     = (const float*)d_in[4];
    const float* g_b     = (const float*)d_in[5];
    const float* g_rm    = (const float*)d_in[6];
    const float* g_rv    = (const float*)d_in[7];
    const float* grp_w   = (const float*)d_in[8];
    const float* grp_b   = (const float*)d_in[9];
    const float* grp_rm  = (const float*)d_in[10];
    const float* grp_rv  = (const float*)d_in[11];
    float* out = (float*)d_out;

    float* pooled = (float*)d_ws;          // B*C
    float* scale  = pooled + B_ * C_;      // B*C
    float* shift  = scale  + B_ * C_;      // B*C

    pool_kernel<<<B_ * C_, 256, 0, stream>>>(x, pooled);
    alpha_scale_kernel<<<B_, 256, 0, stream>>>(pooled, alpha_w, alpha_b,
                                               g_w, g_b, g_rm, g_rv,
                                               grp_w, grp_b, grp_rm, grp_rv,
                                               scale, shift);
    apply_kernel<<<B_ * C_, 256, 0, stream>>>(x, scale, shift, out);
}